// Round 20
// baseline (140.937 us; speedup 1.0000x reference)
//
#include <hip/hip_runtime.h>
#include <cstdint>
#include <cstddef>

using f16   = _Float16;
using half4 = __attribute__((ext_vector_type(4))) _Float16;
using half8 = __attribute__((ext_vector_type(8))) _Float16;
using f32x4 = __attribute__((ext_vector_type(4))) float;
using ull   = unsigned long long;

#define DINL __device__ __forceinline__

// global -> LDS async, 16B per lane. LDS dest wave-uniform base + lane*16.
DINL void gload_lds16(const void* gptr, void* lptr) {
  __builtin_amdgcn_global_load_lds(
      reinterpret_cast<const __attribute__((address_space(1))) uint32_t*>(
          reinterpret_cast<uintptr_t>(gptr)),
      reinterpret_cast<__attribute__((address_space(3))) uint32_t*>(
          reinterpret_cast<uintptr_t>(lptr)),
      16, 0, 0);
}

DINL unsigned pkh(float a, float b) {
  unsigned short ha = __builtin_bit_cast(unsigned short, (f16)a);
  unsigned short hb = __builtin_bit_cast(unsigned short, (f16)b);
  return (unsigned)ha | ((unsigned)hb << 16);
}

struct U4 { unsigned x, y, z, w; };

// x -> 16B A-row: [B0..B5 uniform cubic B-spline, silu(x), 0] as 8 f16.
// Funnel-shift placement; validated rounds 5-19 (absmax 0.03125).
DINL U4 expand_pack(float x) {
  float xs = (x + 3.0f) * 1.5f;
  float mf = floorf(xs);
  int   m  = (int)mf;
  float u = xs - mf, u2 = u * u, u3 = u2 * u, um = 1.0f - u;
  float p3 = u3 * (1.0f / 6.0f);
  float p2 = (1.0f + 3.0f * (u + u2 - u3)) * (1.0f / 6.0f);
  float p1 = (4.0f - 6.0f * u2 + 3.0f * u3) * (1.0f / 6.0f);
  float p0 = um * um * um * (1.0f / 6.0f);
  ull P = (ull)pkh(p0, p1) | ((ull)pkh(p2, p3) << 32);
  if ((unsigned)m > 8u) P = 0;
  int s    = m * 16 - 48;
  int sneg = min(63, max(0, -s));
  int spos = min(63, max(0, s));
  int shi2 = min(63, max(0, s - 64));
  ull rlo = (s < 0) ? (P >> sneg) : ((s < 64) ? (P << spos) : 0ull);
  ull rhi = (s < 0) ? 0ull
                    : ((s < 64) ? ((P >> (63 - spos)) >> 1) : (P << shi2));
  float sil = x / (1.0f + __expf(-x));
  U4 r;
  r.x = (unsigned)rlo;
  r.y = (unsigned)(rlo >> 32);
  r.z = (unsigned)rhi;
  r.w = pkh(sil, 0.0f);
  return r;
}

// Merged weight prep for BOTH layers (one dispatch), PRE-SWIZZLED (rule 21):
// dim slot stored at (d&7)^(n&7). Validated rounds 2-19.
__global__ __launch_bounds__(256)
void prep_w2_kernel(const float* __restrict__ coef1, const float* __restrict__ ssp1,
                    const float* __restrict__ sb1,   f16* __restrict__ Wt1, int n1,
                    const float* __restrict__ coef2, const float* __restrict__ ssp2,
                    const float* __restrict__ sb2,   f16* __restrict__ Wt2,
                    int Din1, int Dout1, int Din2, int Dout2) {
  int idx = blockIdx.x * 256 + threadIdx.x;
  const float *coef, *ssp, *sb;
  f16* Wt;
  int Din, Dout;
  if (idx < n1) {
    coef = coef1; ssp = ssp1; sb = sb1; Wt = Wt1; Din = Din1; Dout = Dout1;
  } else {
    idx -= n1;
    if (idx >= Din2 * Dout2) return;
    coef = coef2; ssp = ssp2; sb = sb2; Wt = Wt2; Din = Din2; Dout = Dout2;
  }
  int n = idx / Din;
  int d = idx - n * Din;
  float s = ssp[(size_t)d * Dout + n];
  const float* c = coef + ((size_t)d * Dout + n) * 6;
  half8 wv;
#pragma unroll
  for (int b = 0; b < 6; ++b) wv[b] = (f16)(c[b] * s);
  wv[6] = (f16)sb[(size_t)d * Dout + n];
  wv[7] = (f16)0.0f;
  int dp = (d & ~7) | ((d & 7) ^ (n & 7));
  *reinterpret_cast<half8*>(Wt + ((size_t)n * Din + dp) * 8) = wv;
}

// ---------------------------------------------------------------------------
// Fused KAN GEMM v20 = r18's 8-phase counted-vmcnt template with the r18 bug
// FIXED: xsrc now includes dim0 (r18's z>0 blocks expanded dims 0..127
// instead of their split-K slice — deterministic wrong answer, not a race;
// the sync structure re-audited clean). BM=256 x BN=256, BK=64, 8 waves
// (2Mx4N, 128x64/wave), dbuf A+B+X = 144KB LDS, 1 blk/CU. Per K-tile, 4
// phases x {frag ds_reads; stage issue; bar; setprio+16 MFMA; bar}; counted
// waits BEFORE their barrier, never vmcnt(0) in-loop:
//   P1-end vmcnt(4): X(t+1) landed, 4 B-stages ride.
//   P3-end lgkmcnt(0)+vmcnt(1): A(t+1) writes retired, B(t+1) landed,
//   X(t+2) rides. sched_barrier(0) after each asm wait (rule #18).
// Numerics identical to v11 (same expand, same per-output MFMA order).
// ---------------------------------------------------------------------------
template <bool BIAS, int NSRC, typename TIN, typename TOUT>
__global__ __launch_bounds__(512, 1)
void kan_gemm8(const TIN* __restrict__ X0, const TIN* __restrict__ X1, int ldx,
               const f16* __restrict__ Wt, int ldw,
               const float* __restrict__ nscale, const float* __restrict__ nbias,
               int N, TOUT* __restrict__ Out, int T) {
  extern __shared__ char smem[];
  f16*  A0v = (f16*)(smem);                    // 32 KB
  f16*  A1v = (f16*)(smem + 32768);            // 32 KB
  f16*  B0v = (f16*)(smem + 65536);            // 32 KB
  f16*  B1v = (f16*)(smem + 98304);            // 32 KB
  char* Xb0 = smem + 131072;                   //  8 KB
  char* Xb1 = smem + 131072 + 8192;            //  8 KB

  const int tid  = threadIdx.x;
  const int lane = tid & 63;
  const int w    = tid >> 6;
  const int l15  = lane & 15, l7 = lane & 7, hi = lane >> 4;
  const int wm   = w >> 2, wn = w & 3;         // 2 x 4 wave grid
  const int m0   = blockIdx.y * 256;
  const int n0   = blockIdx.x * 256;
  const int dim0 = blockIdx.z * (T * 8);       // split-K dim offset
  TOUT* outz = Out + (size_t)blockIdx.z * ((size_t)gridDim.y * 256) * N;

  // B staging: 4 x 16B/thread (2048 chunks): chunk c -> row c>>3, slot c&7.
  const f16* wb[4];
  int bdst[4];
#pragma unroll
  for (int q = 0; q < 4; ++q) {
    int c   = tid + q * 512;
    wb[q]   = Wt + (size_t)(n0 + (c >> 3)) * ldw + (size_t)dim0 * 8 + (c & 7) * 8;
    bdst[q] = c * 8;
  }

  // X staging + expand mapping: thread -> row er = tid>>1, dims ed0 = 4*(tid&1).
  // FIX vs r18: xsrc includes dim0 (split-K slice) in BOTH branches.
  const int er = tid >> 1, ed0 = 4 * (tid & 1), erq = er & 7;
  const TIN* xsrc;
  if constexpr (NSRC == 1) {
    xsrc = X0 + (size_t)(m0 + er) * ldx + dim0 + ed0;
  } else {
    xsrc = (tid < 256) ? (X0 + (size_t)(m0 + tid) * ldx + dim0)
                       : (X1 + (size_t)(m0 + tid - 256) * ldx + dim0);
  }

  // fragment addressing (swizzle identical to v11)
  const int aRow = (wm * 128 + l15) * 64;
  const int bRow = (wn * 64 + l15) * 64;
  const int s0 = 8 * (hi ^ l7);
  const int s1 = 8 * ((4 + hi) ^ l7);

  f32x4 acc[8][4] = {};

  auto stageB2 = [&](f16* Bn, int kB, int qb) {
    gload_lds16(wb[qb] + kB, Bn + bdst[qb]);
    gload_lds16(wb[qb + 1] + kB, Bn + bdst[qb + 1]);
  };
  auto stageX = [&](char* Xw, int dX) {
    gload_lds16(xsrc + dX, Xw + tid * 16);
  };
  auto loadx = [&](const char* Xr, float* xs) {
    if constexpr (NSRC == 1) {
      const float4 v = *reinterpret_cast<const float4*>(
          (const float*)Xr + er * 8 + ed0);
      xs[0] = v.x; xs[1] = v.y; xs[2] = v.z; xs[3] = v.w;
    } else {
      const f16* p = (const f16*)Xr;
      half4 a = *reinterpret_cast<const half4*>(p + er * 8 + ed0);
      half4 b = *reinterpret_cast<const half4*>(p + 2048 + er * 8 + ed0);
#pragma unroll
      for (int j = 0; j < 4; ++j) xs[j] = (float)a[j] + (float)b[j];
    }
  };

  auto TILE = [&](const f16* Ac, const f16* Bc, f16* An, f16* Bn,
                  const char* Xr, char* Xw, int kB, int dX) {
    half8 av[4], bv[4];
    // ---------- P0: kk0, i0-3 ----------
#pragma unroll
    for (int i = 0; i < 4; ++i)
      av[i] = *reinterpret_cast<const half8*>(Ac + aRow + i * 1024 + s0);
#pragma unroll
    for (int j = 0; j < 4; ++j)
      bv[j] = *reinterpret_cast<const half8*>(Bc + bRow + j * 1024 + s0);
    stageB2(Bn, kB, 0);
    __builtin_amdgcn_s_barrier();
    __builtin_amdgcn_s_setprio(1);
#pragma unroll
    for (int i = 0; i < 4; ++i)
#pragma unroll
      for (int j = 0; j < 4; ++j)
        acc[i][j] = __builtin_amdgcn_mfma_f32_16x16x32_f16(av[i], bv[j], acc[i][j], 0, 0, 0);
    __builtin_amdgcn_s_setprio(0);
    __builtin_amdgcn_s_barrier();
    // ---------- P1: kk0, i4-7 ----------
#pragma unroll
    for (int i = 0; i < 4; ++i)
      av[i] = *reinterpret_cast<const half8*>(Ac + aRow + (4 + i) * 1024 + s0);
    stageB2(Bn, kB, 2);
    __builtin_amdgcn_s_barrier();
    __builtin_amdgcn_s_setprio(1);
#pragma unroll
    for (int i = 0; i < 4; ++i)
#pragma unroll
      for (int j = 0; j < 4; ++j)
        acc[4 + i][j] = __builtin_amdgcn_mfma_f32_16x16x32_f16(av[i], bv[j], acc[4 + i][j], 0, 0, 0);
    __builtin_amdgcn_s_setprio(0);
    asm volatile("s_waitcnt vmcnt(4)" ::: "memory");  // X(t+1) landed; B-stages ride
    __builtin_amdgcn_sched_barrier(0);
    __builtin_amdgcn_s_barrier();
    // ---------- P2: kk1, i0-3 + x read + X-stage + expand(2) ----------
#pragma unroll
    for (int i = 0; i < 4; ++i)
      av[i] = *reinterpret_cast<const half8*>(Ac + aRow + i * 1024 + s1);
#pragma unroll
    for (int j = 0; j < 4; ++j)
      bv[j] = *reinterpret_cast<const half8*>(Bc + bRow + j * 1024 + s1);
    float xs[4];
    loadx(Xr, xs);                               // post-barrier: cross-wave safe
    stageX(Xw, dX);
    {
      U4 e0 = expand_pack(xs[0]);
      U4 e1 = expand_pack(xs[1]);
      *reinterpret_cast<U4*>(An + er * 64 + 8 * ((ed0 + 0) ^ erq)) = e0;
      *reinterpret_cast<U4*>(An + er * 64 + 8 * ((ed0 + 1) ^ erq)) = e1;
    }
    __builtin_amdgcn_s_barrier();
    __builtin_amdgcn_s_setprio(1);
#pragma unroll
    for (int i = 0; i < 4; ++i)
#pragma unroll
      for (int j = 0; j < 4; ++j)
        acc[i][j] = __builtin_amdgcn_mfma_f32_16x16x32_f16(av[i], bv[j], acc[i][j], 0, 0, 0);
    __builtin_amdgcn_s_setprio(0);
    __builtin_amdgcn_s_barrier();
    // ---------- P3: kk1, i4-7 + expand(2) + handoff ----------
#pragma unroll
    for (int i = 0; i < 4; ++i)
      av[i] = *reinterpret_cast<const half8*>(Ac + aRow + (4 + i) * 1024 + s1);
    {
      U4 e2 = expand_pack(xs[2]);
      U4 e3 = expand_pack(xs[3]);
      *reinterpret_cast<U4*>(An + er * 64 + 8 * ((ed0 + 2) ^ erq)) = e2;
      *reinterpret_cast<U4*>(An + er * 64 + 8 * ((ed0 + 3) ^ erq)) = e3;
    }
    __builtin_amdgcn_s_barrier();
    __builtin_amdgcn_s_setprio(1);
#pragma unroll
    for (int i = 0; i < 4; ++i)
#pragma unroll
      for (int j = 0; j < 4; ++j)
        acc[4 + i][j] = __builtin_amdgcn_mfma_f32_16x16x32_f16(av[i], bv[j], acc[4 + i][j], 0, 0, 0);
    __builtin_amdgcn_s_setprio(0);
    asm volatile("s_waitcnt lgkmcnt(0)" ::: "memory"); // A[nxt] writes retired
    asm volatile("s_waitcnt vmcnt(1)" ::: "memory");   // B(t+1) landed; X(t+2) rides
    __builtin_amdgcn_sched_barrier(0);
    __builtin_amdgcn_s_barrier();                      // handoff
  };

  // ---- prologue: X(0)->Xb0, B(0)->B0v, X(1)->Xb1; expand A(0)->A0v ----
  stageX(Xb0, 0);                               // op 1
  stageB2(B0v, 0, 0);                           // ops 2-3
  stageB2(B0v, 0, 2);                           // ops 4-5
  stageX(Xb1, (T > 1 ? 8 : 0));                 // op 6
  asm volatile("s_waitcnt vmcnt(5)" ::: "memory");  // X(0) landed
  __builtin_amdgcn_sched_barrier(0);
  __builtin_amdgcn_s_barrier();                 // cross-wave X(0) visible
  {
    float xs[4];
    loadx(Xb0, xs);
#pragma unroll
    for (int j = 0; j < 4; ++j) {
      U4 e = expand_pack(xs[j]);
      *reinterpret_cast<U4*>(A0v + er * 64 + 8 * ((ed0 + j) ^ erq)) = e;
    }
  }
  asm volatile("s_waitcnt lgkmcnt(0)" ::: "memory");
  asm volatile("s_waitcnt vmcnt(1)" ::: "memory");    // B(0) landed; X(1) rides
  __builtin_amdgcn_sched_barrier(0);
  __builtin_amdgcn_s_barrier();

  // ---- main loop: pairs of K-tiles, static buffer names ----
  const int npairs = T >> 1;
  for (int p = 0; p < npairs; ++p) {
    const int t0 = 2 * p, t1 = 2 * p + 1;
    const int kB0 = (t0 + 1 < T ? t0 + 1 : T - 1) * 64;
    const int dX0 = (t0 + 2 < T ? t0 + 2 : T - 1) * 8;
    const int kB1 = (t1 + 1 < T ? t1 + 1 : T - 1) * 64;
    const int dX1 = (t1 + 2 < T ? t1 + 2 : T - 1) * 8;
    TILE(A0v, B0v, A1v, B1v, Xb1, Xb0, kB0, dX0);
    TILE(A1v, B1v, A0v, B0v, Xb0, Xb1, kB1, dX1);
  }

  // ---- epilogue: Out = ns*acc (+ nb on z==0) ----
#pragma unroll
  for (int j = 0; j < 4; ++j) {
    int col   = n0 + wn * 64 + j * 16 + l15;
    float nsv = nscale[col];
    float nbv = (BIAS && blockIdx.z == 0) ? nbias[col] : 0.0f;
#pragma unroll
    for (int i = 0; i < 8; ++i) {
      int rb = m0 + wm * 128 + i * 16 + hi * 4;
#pragma unroll
      for (int r = 0; r < 4; ++r)
        outz[(size_t)(rb + r) * N + col] = (TOUT)(nsv * acc[i][j][r] + nbv);
    }
  }
}

// ---------------------------------------------------------------------------
// sum of 4 f16 partials + node_bias2 + residual -> LN(256) -> exact GELU
// ---------------------------------------------------------------------------
__global__ __launch_bounds__(256)
void ln_gelu_kernel(const f16* __restrict__ P, size_t zstride,
                    const float* __restrict__ X,  const float* __restrict__ nb2,
                    const float* __restrict__ gamma, const float* __restrict__ beta,
                    float* __restrict__ out, int rows) {
  int row  = blockIdx.x * 4 + (threadIdx.x >> 6);
  int lane = threadIdx.x & 63;
  if (row >= rows) return;
  const size_t base = (size_t)row * 256 + lane * 4;
  const float4 xr = *reinterpret_cast<const float4*>(X + base);
  const float4 nb = *reinterpret_cast<const float4*>(nb2 + lane * 4);
  const float4 g  = *reinterpret_cast<const float4*>(gamma + lane * 4);
  const float4 be = *reinterpret_cast<const float4*>(beta + lane * 4);
  float h[4] = { (&nb.x)[0] + (&xr.x)[0], (&nb.x)[1] + (&xr.x)[1],
                 (&nb.x)[2] + (&xr.x)[2], (&nb.x)[3] + (&xr.x)[3] };
#pragma unroll
  for (int z = 0; z < 4; ++z) {
    const half4 p4 = *reinterpret_cast<const half4*>(P + z * zstride + base);
#pragma unroll
    for (int j = 0; j < 4; ++j) h[j] += (float)p4[j];
  }
  float s = h[0] + h[1] + h[2] + h[3];
#pragma unroll
  for (int o = 32; o >= 1; o >>= 1) s += __shfl_xor(s, o);
  float mu = s * (1.0f / 256.0f);
  float vs = 0.f;
#pragma unroll
  for (int j = 0; j < 4; ++j) { float d = h[j] - mu; vs += d * d; }
#pragma unroll
  for (int o = 32; o >= 1; o >>= 1) vs += __shfl_xor(vs, o);
  float inv = rsqrtf(vs * (1.0f / 256.0f) + 1e-5f);
  float o4[4];
#pragma unroll
  for (int j = 0; j < 4; ++j) {
    float v = (h[j] - mu) * inv * (&g.x)[j] + (&be.x)[j];
    o4[j] = 0.5f * v * (1.0f + erff(v * 0.70710678118654752f));
  }
  *reinterpret_cast<float4*>(out + (size_t)row * 256 + lane * 4) =
      make_float4(o4[0], o4[1], o4[2], o4[3]);
}

// ---------------------------------------------------------------------------
extern "C" void kernel_launch(void* const* d_in, const int* in_sizes, int n_in,
                              void* d_out, int out_size, void* d_ws, size_t ws_size,
                              hipStream_t stream) {
  (void)in_sizes; (void)n_in; (void)out_size; (void)ws_size;
  const float* x     = (const float*)d_in[0];
  const float* coef1 = (const float*)d_in[2];
  const float* sb1   = (const float*)d_in[3];
  const float* ssp1  = (const float*)d_in[4];
  const float* ns1   = (const float*)d_in[5];
  const float* nb1   = (const float*)d_in[6];
  const float* coef2 = (const float*)d_in[8];
  const float* sb2   = (const float*)d_in[9];
  const float* ssp2  = (const float*)d_in[10];
  const float* ns2   = (const float*)d_in[11];
  const float* nb2   = (const float*)d_in[12];
  const float* lgam  = (const float*)d_in[13];
  const float* lbet  = (const float*)d_in[14];
  float* out = (float*)d_out;

  const int Ntok = 16 * 1024;
  const int D0 = 256, D1 = 512, D2 = 256;
  const size_t LDS = 147456;   // 144 KB dynamic

  // ws: h1 partials 2 x [Ntok,512] f16 | part 4 x [Ntok,256] f16 | Wt1 | Wt2
  char* ws     = (char*)d_ws;
  f16*  h1p    = (f16*)ws;
  size_t h1z   = (size_t)Ntok * D1;
  size_t off   = 2 * h1z * sizeof(f16);
  f16*  part   = (f16*)(ws + off);
  size_t partz = (size_t)Ntok * D2;
  off += 4 * partz * sizeof(f16);
  f16* Wt1 = (f16*)(ws + off);
  off += (size_t)D1 * D0 * 8 * sizeof(f16);
  f16* Wt2 = (f16*)(ws + off);

  // merged weight prep: one dispatch covers both layers
  const int n1 = D0 * D1, n2 = D1 * D2;
  prep_w2_kernel<<<(n1 + n2 + 255) / 256, 256, 0, stream>>>(
      coef1, ssp1, sb1, Wt1, n1, coef2, ssp2, sb2, Wt2, D0, D1, D1, D2);

  // layer 1: [16384 x 2048] x [512 x 2048]^T, split-K=2 -> 2x64x2 = 256 blocks
  // (1/CU). T = (256/2)/8 = 16 K-tiles. Partials: z0 = ns*acc+nb, z1 = ns*acc.
  kan_gemm8<true, 1, float, f16><<<dim3(D1 / 256, Ntok / 256, 2), 512, LDS, stream>>>(
      x, nullptr, D0, Wt1, D0 * 8, ns1, nb1, D1, h1p, D0 / 16);

  // layer 2: A = h1p0 + h1p1 (summed in X-stage read); split-K=4 -> 256 blocks.
  kan_gemm8<false, 2, f16, f16><<<dim3(D2 / 256, Ntok / 256, 4), 512, LDS, stream>>>(
      h1p, h1p + h1z, D1, Wt2, D1 * 8, ns2, nullptr, D2, part, D1 / 32);

  // reduce 4 partials + bias + residual + LN + GELU
  ln_gelu_kernel<<<Ntok / 4, 256, 0, stream>>>(
      part, partz, x, nb2, lgam, lbet, out, Ntok);
}

// Round 21
// 115.988 us; speedup vs baseline: 1.2151x; 1.2151x over previous
//
#include <hip/hip_runtime.h>
#include <cstdint>
#include <cstddef>

using f16   = _Float16;
using half4 = __attribute__((ext_vector_type(4))) _Float16;
using half8 = __attribute__((ext_vector_type(8))) _Float16;
using f32x4 = __attribute__((ext_vector_type(4))) float;
using ull   = unsigned long long;

#define DINL __device__ __forceinline__

// global -> LDS async, 16B per lane. LDS dest wave-uniform base + lane*16.
DINL void gload_lds16(const void* gptr, void* lptr) {
  __builtin_amdgcn_global_load_lds(
      reinterpret_cast<const __attribute__((address_space(1))) uint32_t*>(
          reinterpret_cast<uintptr_t>(gptr)),
      reinterpret_cast<__attribute__((address_space(3))) uint32_t*>(
          reinterpret_cast<uintptr_t>(lptr)),
      16, 0, 0);
}

DINL unsigned pkh(float a, float b) {
  unsigned short ha = __builtin_bit_cast(unsigned short, (f16)a);
  unsigned short hb = __builtin_bit_cast(unsigned short, (f16)b);
  return (unsigned)ha | ((unsigned)hb << 16);
}

struct U4 { unsigned x, y, z, w; };

// x -> 16B A-row: [B0..B5 uniform cubic B-spline, silu(x), 0] as 8 f16.
// Funnel-shift placement; validated rounds 5-20 (absmax 0.03125).
DINL U4 expand_pack(float x) {
  float xs = (x + 3.0f) * 1.5f;
  float mf = floorf(xs);
  int   m  = (int)mf;
  float u = xs - mf, u2 = u * u, u3 = u2 * u, um = 1.0f - u;
  float p3 = u3 * (1.0f / 6.0f);
  float p2 = (1.0f + 3.0f * (u + u2 - u3)) * (1.0f / 6.0f);
  float p1 = (4.0f - 6.0f * u2 + 3.0f * u3) * (1.0f / 6.0f);
  float p0 = um * um * um * (1.0f / 6.0f);
  ull P = (ull)pkh(p0, p1) | ((ull)pkh(p2, p3) << 32);
  if ((unsigned)m > 8u) P = 0;
  int s    = m * 16 - 48;
  int sneg = min(63, max(0, -s));
  int spos = min(63, max(0, s));
  int shi2 = min(63, max(0, s - 64));
  ull rlo = (s < 0) ? (P >> sneg) : ((s < 64) ? (P << spos) : 0ull);
  ull rhi = (s < 0) ? 0ull
                    : ((s < 64) ? ((P >> (63 - spos)) >> 1) : (P << shi2));
  float sil = x / (1.0f + __expf(-x));
  U4 r;
  r.x = (unsigned)rlo;
  r.y = (unsigned)(rlo >> 32);
  r.z = (unsigned)rhi;
  r.w = pkh(sil, 0.0f);
  return r;
}

// Merged weight prep for BOTH layers (one dispatch), PRE-SWIZZLED (rule 21):
// dim slot stored at (d&7)^(n&7) so linear global_load_lds yields the
// swizzled LDS tile. Validated rounds 2-19.
__global__ __launch_bounds__(256)
void prep_w2_kernel(const float* __restrict__ coef1, const float* __restrict__ ssp1,
                    const float* __restrict__ sb1,   f16* __restrict__ Wt1, int n1,
                    const float* __restrict__ coef2, const float* __restrict__ ssp2,
                    const float* __restrict__ sb2,   f16* __restrict__ Wt2,
                    int Din1, int Dout1, int Din2, int Dout2) {
  int idx = blockIdx.x * 256 + threadIdx.x;
  const float *coef, *ssp, *sb;
  f16* Wt;
  int Din, Dout;
  if (idx < n1) {
    coef = coef1; ssp = ssp1; sb = sb1; Wt = Wt1; Din = Din1; Dout = Dout1;
  } else {
    idx -= n1;
    if (idx >= Din2 * Dout2) return;
    coef = coef2; ssp = ssp2; sb = sb2; Wt = Wt2; Din = Din2; Dout = Dout2;
  }
  int n = idx / Din;
  int d = idx - n * Din;
  float s = ssp[(size_t)d * Dout + n];
  const float* c = coef + ((size_t)d * Dout + n) * 6;
  half8 wv;
#pragma unroll
  for (int b = 0; b < 6; ++b) wv[b] = (f16)(c[b] * s);
  wv[6] = (f16)sb[(size_t)d * Dout + n];
  wv[7] = (f16)0.0f;
  int dp = (d & ~7) | ((d & 7) ^ (n & 7));
  *reinterpret_cast<half8*>(Wt + ((size_t)n * Din + dp) * 8) = wv;
}

// ---------------------------------------------------------------------------
// Fused KAN GEMM v11 (best measured: 116.3us total, absmax 0.03125):
// BM=64 x BN=256, 8 waves (2x4, 32x64/wave), BK=64, static 80KB LDS dbuf,
// 1 barrier/step, K-loop unrolled x2 with static buffer names + peeled tail.
// T5 setprio around MFMA cluster; f16 h1/partials (templated dtypes).
// Session verdict (20 rounds): this 2-phase dbuf structure is the verified
// frontier (~660 TF/GEMM = measured 2-phase ceiling); counted-vmcnt,
// single-buffer, direct-B, and 8-phase variants all raced or regressed.
// ---------------------------------------------------------------------------
template <bool BIAS, typename TIN, typename TOUT>
__global__ __launch_bounds__(512, 4)
void kan_gemm(const TIN* __restrict__ X, int ldx,
              const f16* __restrict__ Wt, int ldw,
              const float* __restrict__ nscale, const float* __restrict__ nbias,
              int N, TOUT* __restrict__ Out, int nsteps) {
  __shared__ alignas(16) f16 A0[64 * 64];      //  8 KB
  __shared__ alignas(16) f16 A1[64 * 64];      //  8 KB
  __shared__ alignas(16) f16 B0[256 * 64];     // 32 KB
  __shared__ alignas(16) f16 B1[256 * 64];     // 32 KB

  const int tid  = threadIdx.x;
  const int w    = tid >> 6;
  const int lane = tid & 63;
  const int l15  = lane & 15, l7 = lane & 7, hi = lane >> 4;
  const int wm   = w >> 2, wn = w & 3;         // wave grid 2 x 4
  const int m0   = blockIdx.y * 64;
  const int n0   = blockIdx.x * 256;
  const int dim0 = blockIdx.z * (nsteps * 8);  // split-K dim offset
  TOUT* outz = Out + (size_t)blockIdx.z * ((size_t)gridDim.y * 64) * N;

  // A: 1 element/thread/step (64 rows x 8 dims = 512); asrc is DIM-indexed.
  const int ar = tid >> 3, ad = tid & 7;
  const TIN* asrc = X + (size_t)(m0 + ar) * ldx + dim0 + ad;
  const int aoff = ar * 64 + 8 * (ad ^ (ar & 7));

  // B: 4 x 16B chunks/thread (256 rows x 8 slots = 2048 chunks)
  const f16* wb[4];
  int ldsb[4];
#pragma unroll
  for (int q = 0; q < 4; ++q) {
    int c   = tid + q * 512;
    wb[q]   = Wt + (size_t)(n0 + (c >> 3)) * ldw + (size_t)dim0 * 8 + (c & 7) * 8;
    ldsb[q] = c * 8;
  }

  f32x4 acc[2][4] = {};

  auto stageB = [&](f16* buf, int k0) {
#pragma unroll
    for (int q = 0; q < 4; ++q) gload_lds16(wb[q] + k0, buf + ldsb[q]);
  };

  auto compute = [&](const f16* bA, const f16* bB) {
    __builtin_amdgcn_s_setprio(1);             // T5: favor MFMA-issuing wave
#pragma unroll
    for (int kk = 0; kk < 2; ++kk) {
      const int sl = kk * 4 + hi;
      half8 av[2], bv[4];
#pragma unroll
      for (int i = 0; i < 2; ++i)
        av[i] = *reinterpret_cast<const half8*>(
            bA + (wm * 32 + i * 16 + l15) * 64 + 8 * (sl ^ l7));
#pragma unroll
      for (int j = 0; j < 4; ++j)
        bv[j] = *reinterpret_cast<const half8*>(
            bB + (wn * 64 + j * 16 + l15) * 64 + 8 * (sl ^ l7));
#pragma unroll
      for (int i = 0; i < 2; ++i)
#pragma unroll
        for (int j = 0; j < 4; ++j)
          acc[i][j] = __builtin_amdgcn_mfma_f32_16x16x32_f16(av[i], bv[j], acc[i][j], 0, 0, 0);
    }
    __builtin_amdgcn_s_setprio(0);
  };

  auto writeA = [&](f16* buf, U4 e) {
    *reinterpret_cast<U4*>(buf + aoff) = e;
  };

  // ---- prologue: tile 0 in A0/B0; xn = x(1) in flight ----
  {
    float xa = (float)asrc[0];
    stageB(B0, 0);
    writeA(A0, expand_pack(xa));
  }
  float xn = (float)asrc[8];
  __syncthreads();

  // ---- steady state: 2 tiles per iteration, static buffers ----
  const TIN* ap = asrc + 16;                   // x(s+2) position (dim units)
  const int npairs = (nsteps - 2) >> 1;
  int k = 64;                                  // staging k0 for tile s+1
  for (int p = 0; p < npairs; ++p) {
    // half A: compute tile s (A0/B0); stage B(s+1)->B1; expand x(s+1)->A1
    stageB(B1, k);
    float xa2 = (float)ap[0];                  // x(s+2), issued early
    compute(A0, B0);
    writeA(A1, expand_pack(xn));
    __syncthreads();
    // half B: compute tile s+1 (A1/B1); stage B(s+2)->B0; expand x(s+2)->A0
    stageB(B0, k + 64);
    xn = (float)ap[8];                         // x(s+3), issued early
    compute(A1, B1);
    writeA(A0, expand_pack(xa2));
    __syncthreads();
    ap += 16;
    k  += 128;
  }

  // ---- tail: tiles nsteps-2 (A0/B0) and nsteps-1 (A1/B1) ----
  stageB(B1, k);                               // k == (nsteps-1)*64
  compute(A0, B0);
  writeA(A1, expand_pack(xn));
  __syncthreads();
  compute(A1, B1);

  // ---- epilogue: Out = ns*acc (+ nb) ----
#pragma unroll
  for (int j = 0; j < 4; ++j) {
    int col   = n0 + wn * 64 + j * 16 + l15;
    float nsv = nscale[col];
    float nbv = BIAS ? nbias[col] : 0.0f;
#pragma unroll
    for (int i = 0; i < 2; ++i) {
      int rb = m0 + wm * 32 + i * 16 + hi * 4;
#pragma unroll
      for (int r = 0; r < 4; ++r)
        outz[(size_t)(rb + r) * N + col] = (TOUT)(nsv * acc[i][j][r] + nbv);
    }
  }
}

// ---------------------------------------------------------------------------
// f16 partial0 + f16 partial1 + node_bias2 + residual -> LN(256) -> exact GELU
// ---------------------------------------------------------------------------
__global__ __launch_bounds__(256)
void ln_gelu_kernel(const f16* __restrict__ P0, const f16* __restrict__ P1,
                    const float* __restrict__ X,  const float* __restrict__ nb2,
                    const float* __restrict__ gamma, const float* __restrict__ beta,
                    float* __restrict__ out, int rows) {
  int row  = blockIdx.x * 4 + (threadIdx.x >> 6);
  int lane = threadIdx.x & 63;
  if (row >= rows) return;
  const half4  a4 = *reinterpret_cast<const half4*>(P0 + (size_t)row * 256 + lane * 4);
  const half4  b4 = *reinterpret_cast<const half4*>(P1 + (size_t)row * 256 + lane * 4);
  const float4 xr = *reinterpret_cast<const float4*>(X  + (size_t)row * 256 + lane * 4);
  const float4 nb = *reinterpret_cast<const float4*>(nb2 + lane * 4);
  const float4 g  = *reinterpret_cast<const float4*>(gamma + lane * 4);
  const float4 be = *reinterpret_cast<const float4*>(beta + lane * 4);
  float h[4];
#pragma unroll
  for (int j = 0; j < 4; ++j)
    h[j] = (float)a4[j] + (float)b4[j] + (&nb.x)[j] + (&xr.x)[j];
  float s = h[0] + h[1] + h[2] + h[3];
#pragma unroll
  for (int o = 32; o >= 1; o >>= 1) s += __shfl_xor(s, o);
  float mu = s * (1.0f / 256.0f);
  float vs = 0.f;
#pragma unroll
  for (int j = 0; j < 4; ++j) { float d = h[j] - mu; vs += d * d; }
#pragma unroll
  for (int o = 32; o >= 1; o >>= 1) vs += __shfl_xor(vs, o);
  float inv = rsqrtf(vs * (1.0f / 256.0f) + 1e-5f);
  float o4[4];
#pragma unroll
  for (int j = 0; j < 4; ++j) {
    float v = (h[j] - mu) * inv * (&g.x)[j] + (&be.x)[j];
    o4[j] = 0.5f * v * (1.0f + erff(v * 0.70710678118654752f));
  }
  *reinterpret_cast<float4*>(out + (size_t)row * 256 + lane * 4) =
      make_float4(o4[0], o4[1], o4[2], o4[3]);
}

// ---------------------------------------------------------------------------
extern "C" void kernel_launch(void* const* d_in, const int* in_sizes, int n_in,
                              void* d_out, int out_size, void* d_ws, size_t ws_size,
                              hipStream_t stream) {
  (void)in_sizes; (void)n_in; (void)out_size; (void)ws_size;
  const float* x     = (const float*)d_in[0];
  const float* coef1 = (const float*)d_in[2];
  const float* sb1   = (const float*)d_in[3];
  const float* ssp1  = (const float*)d_in[4];
  const float* ns1   = (const float*)d_in[5];
  const float* nb1   = (const float*)d_in[6];
  const float* coef2 = (const float*)d_in[8];
  const float* sb2   = (const float*)d_in[9];
  const float* ssp2  = (const float*)d_in[10];
  const float* ns2   = (const float*)d_in[11];
  const float* nb2   = (const float*)d_in[12];
  const float* lgam  = (const float*)d_in[13];
  const float* lbet  = (const float*)d_in[14];
  float* out = (float*)d_out;

  const int Ntok = 16 * 1024;
  const int D0 = 256, D1 = 512, D2 = 256;

  // ws: h1 [Ntok,512] f16 (16.8MB) | part [2][Ntok,256] f16 (16.8MB) | Wt1 | Wt2
  char* ws    = (char*)d_ws;
  f16*  h1    = (f16*)ws;
  size_t off  = (size_t)Ntok * D1 * sizeof(f16);
  f16*  part  = (f16*)(ws + off);
  off += (size_t)2 * Ntok * D2 * sizeof(f16);
  f16* Wt1 = (f16*)(ws + off);
  off += (size_t)D1 * D0 * 8 * sizeof(f16);
  f16* Wt2 = (f16*)(ws + off);

  // merged weight prep: one dispatch covers both layers
  const int n1 = D0 * D1, n2 = D1 * D2;
  prep_w2_kernel<<<(n1 + n2 + 255) / 256, 256, 0, stream>>>(
      coef1, ssp1, sb1, Wt1, n1, coef2, ssp2, sb2, Wt2, D0, D1, D1, D2);

  // layer 1: [16384 x 2048] x [512 x 2048]^T -> h1 (f16). 512 blocks, 2/CU.
  kan_gemm<true, float, f16><<<dim3(D1 / 256, Ntok / 64, 1), 512, 0, stream>>>(
      x, D0, Wt1, D0 * 8, ns1, nb1, D1, h1, D0 / 8);

  // layer 2: full-width N=256, split-K=2 -> 512 blocks; f16 partials ns2*acc.
  kan_gemm<false, f16, f16><<<dim3(D2 / 256, Ntok / 64, 2), 512, 0, stream>>>(
      h1, D1, Wt2, D1 * 8, ns2, nullptr, D2, part, D1 / 16);

  // reduce partials + bias + residual + LN + GELU
  ln_gelu_kernel<<<Ntok / 4, 256, 0, stream>>>(
      part, part + (size_t)Ntok * D2, x, nb2, lgam, lbet, out, Ntok);
}